// Round 1
// baseline (1147.595 us; speedup 1.0000x reference)
//
#include <hip/hip_runtime.h>
#include <hip/hip_bf16.h>
#include <math.h>

#define D 768
#define NE 8
#define NTOK 6192      // 32*129 + 16*129
#define MEN_TOK0 4128  // 32*129
#define LISTCAP 6192

// Map concatenated token index -> source row pointer (virtual concat, no copy).
__device__ __forceinline__ const float* token_row(int t,
    const float* __restrict__ ecls, const float* __restrict__ etok,
    const float* __restrict__ mcls, const float* __restrict__ mtok) {
  if (t < MEN_TOK0) {
    int n = t / 129, s = t - n * 129;
    return (s == 0) ? (ecls + n * D) : (etok + (size_t)(n * 128 + s - 1) * D);
  } else {
    int tm = t - MEN_TOK0;
    int b = tm / 129, s = tm - b * 129;
    return (s == 0) ? (mcls + b * D) : (mtok + (size_t)(b * 128 + s - 1) * D);
  }
}

// ---------------- gate: top-2 of (x @ gate_w + gate_b), build per-expert lists
__global__ __launch_bounds__(256) void gate_kernel(
    const float* __restrict__ ecls, const float* __restrict__ etok,
    const float* __restrict__ mcls, const float* __restrict__ mtok,
    const float* __restrict__ gate_w, const float* __restrict__ gate_b,
    int* __restrict__ cnt, int* __restrict__ lst_idx, float* __restrict__ lst_w) {
  int t = blockIdx.x * 4 + (threadIdx.x >> 6);
  if (t >= NTOK) return;
  int lane = threadIdx.x & 63;
  const float* xr = token_row(t, ecls, etok, mcls, mtok);
  float acc[NE];
#pragma unroll
  for (int e = 0; e < NE; ++e) acc[e] = 0.f;
  for (int d = lane; d < D; d += 64) {
    float xv = xr[d];
#pragma unroll
    for (int e = 0; e < NE; ++e) acc[e] += xv * gate_w[d * NE + e];
  }
#pragma unroll
  for (int e = 0; e < NE; ++e) {
#pragma unroll
    for (int off = 32; off > 0; off >>= 1) acc[e] += __shfl_down(acc[e], off);
  }
  if (lane == 0) {
    float lg[NE];
#pragma unroll
    for (int e = 0; e < NE; ++e) lg[e] = acc[e] + gate_b[e];
    int e1 = 0;
#pragma unroll
    for (int e = 1; e < NE; ++e) if (lg[e] > lg[e1]) e1 = e;
    int e2 = (e1 == 0) ? 1 : 0;
#pragma unroll
    for (int e = 0; e < NE; ++e) {
      if (e != e1 && lg[e] > lg[e2]) e2 = e;
    }
    // normalized top-2 softmax == 2-way softmax over top-2 logits
    float w1 = 1.f / (1.f + expf(lg[e2] - lg[e1]));
    float w2 = 1.f - w1;
    int p1 = atomicAdd(&cnt[e1], 1);
    lst_idx[e1 * LISTCAP + p1] = t;
    lst_w [e1 * LISTCAP + p1] = w1;
    int p2 = atomicAdd(&cnt[e2], 1);
    lst_idx[e2 * LISTCAP + p2] = t;
    lst_w [e2 * LISTCAP + p2] = w2;
  }
}

// ---------------- grouped expert GEMM: MOE[t,:] += w * (x_t @ exp_w[e] + exp_b[e])
__global__ __launch_bounds__(256) void moe_expert_kernel(
    const float* __restrict__ ecls, const float* __restrict__ etok,
    const float* __restrict__ mcls, const float* __restrict__ mtok,
    const float* __restrict__ exp_w, const float* __restrict__ exp_b,
    const int* __restrict__ cnt, const int* __restrict__ lst_idx,
    const float* __restrict__ lst_w, float* __restrict__ MOE) {
  int e = blockIdx.z;
  int count = cnt[e];
  int t0 = blockIdx.x * 64;
  if (t0 >= count) return;
  int o0 = blockIdx.y * 64;

  __shared__ float As[64][17];
  __shared__ float Bs[16][65];
  __shared__ const float* sptr[64];
  __shared__ int   stok[64];
  __shared__ float sw[64];

  int tid = threadIdx.x;
  if (tid < 64) {
    int p = t0 + tid;
    int tok; float w;
    if (p < count) { tok = lst_idx[e * LISTCAP + p]; w = lst_w[e * LISTCAP + p]; }
    else           { tok = 0; w = 0.f; }
    stok[tid] = tok; sw[tid] = w;
    sptr[tid] = token_row(tok, ecls, etok, mcls, mtok);
  }
  __syncthreads();

  int tx = tid & 15, ty = tid >> 4;
  float acc[4][4] = {};
  const float* W = exp_w + (size_t)e * D * D;

  for (int k0 = 0; k0 < D; k0 += 16) {
#pragma unroll
    for (int i = 0; i < 4; ++i) {
      int row = i * 16 + ty;
      As[row][tx] = sptr[row][k0 + tx];
    }
#pragma unroll
    for (int i = 0; i < 4; ++i) {
      Bs[ty][i * 16 + tx] = W[(size_t)(k0 + ty) * D + o0 + i * 16 + tx];
    }
    __syncthreads();
#pragma unroll
    for (int k = 0; k < 16; ++k) {
      float a[4], bb[4];
#pragma unroll
      for (int i = 0; i < 4; ++i) a[i] = As[ty * 4 + i][k];
#pragma unroll
      for (int j = 0; j < 4; ++j) bb[j] = Bs[k][tx * 4 + j];
#pragma unroll
      for (int i = 0; i < 4; ++i)
#pragma unroll
        for (int j = 0; j < 4; ++j) acc[i][j] += a[i] * bb[j];
    }
    __syncthreads();
  }

#pragma unroll
  for (int i = 0; i < 4; ++i) {
    int row = ty * 4 + i;
    float w = sw[row];
    if (w != 0.f) {
      int tok = stok[row];
#pragma unroll
      for (int j = 0; j < 4; ++j) {
        int o = o0 + tx * 4 + j;
        atomicAdd(&MOE[(size_t)tok * D + o], w * (acc[i][j] + exp_b[e * D + o]));
      }
    }
  }
}

// ---------------- QKV projections from MoE token rows
__global__ __launch_bounds__(256) void qkv_kernel(
    const float* __restrict__ MOE,
    const float* __restrict__ wq, const float* __restrict__ bq,
    const float* __restrict__ wk, const float* __restrict__ bk,
    const float* __restrict__ wv, const float* __restrict__ bv,
    float* __restrict__ Q, float* __restrict__ K, float* __restrict__ V) {
  int z = blockIdx.z;
  int Mrows = (z == 0) ? 4096 : 2048;
  if (blockIdx.x * 64 >= Mrows) return;
  const float* W    = (z == 0) ? wq : ((z == 1) ? wk : wv);
  const float* bias = (z == 0) ? bq : ((z == 1) ? bk : bv);
  float* OUT        = (z == 0) ? Q  : ((z == 1) ? K  : V);
  int base = (z == 0) ? 0 : MEN_TOK0;
  int r0 = blockIdx.x * 64, o0 = blockIdx.y * 64;

  __shared__ float As[64][17];
  __shared__ float Bs[16][65];
  int tid = threadIdx.x;
  int tx = tid & 15, ty = tid >> 4;
  float acc[4][4] = {};

  for (int k0 = 0; k0 < D; k0 += 16) {
#pragma unroll
    for (int i = 0; i < 4; ++i) {
      int row = i * 16 + ty;
      int r = r0 + row;
      int mrow = base + (r >> 7) * 129 + 1 + (r & 127);
      As[row][tx] = MOE[(size_t)mrow * D + k0 + tx];
    }
#pragma unroll
    for (int i = 0; i < 4; ++i) {
      Bs[ty][i * 16 + tx] = W[(size_t)(k0 + ty) * D + o0 + i * 16 + tx];
    }
    __syncthreads();
#pragma unroll
    for (int k = 0; k < 16; ++k) {
      float a[4], bb[4];
#pragma unroll
      for (int i = 0; i < 4; ++i) a[i] = As[ty * 4 + i][k];
#pragma unroll
      for (int j = 0; j < 4; ++j) bb[j] = Bs[k][tx * 4 + j];
#pragma unroll
      for (int i = 0; i < 4; ++i)
#pragma unroll
        for (int j = 0; j < 4; ++j) acc[i][j] += a[i] * bb[j];
    }
    __syncthreads();
  }

#pragma unroll
  for (int i = 0; i < 4; ++i) {
    int r = r0 + ty * 4 + i;
#pragma unroll
    for (int j = 0; j < 4; ++j) {
      int o = o0 + tx * 4 + j;
      OUT[(size_t)r * D + o] = acc[i][j] + bias[o];
    }
  }
}

__device__ __forceinline__ float blockSum(float v, volatile float* red, int tid) {
#pragma unroll
  for (int off = 32; off > 0; off >>= 1) v += __shfl_down(v, off);
  __syncthreads();
  if ((tid & 63) == 0) red[tid >> 6] = v;
  __syncthreads();
  return red[0] + red[1] + red[2] + red[3];
}

// ---------------- fused attention + mean_l + LayerNorm + final scores
// One block per (b, n). scores(l,m) -> softmax(m) -> colmean pbar(m) -> ctx = pbar@V
// -> LN -> out[b,n] = 0.5*(ent_cls_moe[n].ctx_ln + mcls[b].ecls[n])
__global__ __launch_bounds__(256) void attn_kernel(
    const float* __restrict__ Q, const float* __restrict__ Kb, const float* __restrict__ Vb,
    const float* __restrict__ MOE, const float* __restrict__ ecls, const float* __restrict__ mcls,
    const float* __restrict__ ln_w, const float* __restrict__ ln_b,
    float* __restrict__ out) {
  int b = blockIdx.x, n = blockIdx.y;
  __shared__ float S[64 * 129];   // 64 rows (l-chunk) x 128 cols (m), padded
  __shared__ float Qs[64][9];
  __shared__ float Ks[128][9];
  __shared__ float pbar[128];
  __shared__ float red[4];

  int tid = threadIdx.x;
  int tx = tid & 15, ty = tid >> 4;
  if (tid < 128) pbar[tid] = 0.f;
  const float* kbase = Kb + (size_t)b * 128 * D;
  const float scale = 0.03608439182435161f; // 1/sqrt(768)

  for (int chunk = 0; chunk < 2; ++chunk) {
    const float* qbase = Q + (size_t)(n * 128 + chunk * 64) * D;
    float acc[4][8];
#pragma unroll
    for (int i = 0; i < 4; ++i)
#pragma unroll
      for (int j = 0; j < 8; ++j) acc[i][j] = 0.f;
    __syncthreads(); // protect S/pbar reuse across chunks

    for (int k0 = 0; k0 < D; k0 += 8) {
      int col = tid & 7, rowb = tid >> 3; // rowb 0..31
      Qs[rowb][col]      = qbase[(size_t)rowb * D + k0 + col];
      Qs[rowb + 32][col] = qbase[(size_t)(rowb + 32) * D + k0 + col];
#pragma unroll
      for (int i = 0; i < 4; ++i)
        Ks[i * 32 + rowb][col] = kbase[(size_t)(i * 32 + rowb) * D + k0 + col];
      __syncthreads();
#pragma unroll
      for (int k = 0; k < 8; ++k) {
        float a[4], bb[8];
#pragma unroll
        for (int i = 0; i < 4; ++i) a[i] = Qs[ty * 4 + i][k];
#pragma unroll
        for (int j = 0; j < 8; ++j) bb[j] = Ks[tx * 8 + j][k];
#pragma unroll
        for (int i = 0; i < 4; ++i)
#pragma unroll
          for (int j = 0; j < 8; ++j) acc[i][j] += a[i] * bb[j];
      }
      __syncthreads();
    }

#pragma unroll
    for (int i = 0; i < 4; ++i)
#pragma unroll
      for (int j = 0; j < 8; ++j)
        S[(ty * 4 + i) * 129 + tx * 8 + j] = acc[i][j];
    __syncthreads();

    // row softmax: 4 threads per row, 32 cols each
    {
      int l = tid >> 2, qq = tid & 3;
      int base = l * 129 + qq * 32;
      float mx = -1e30f;
      for (int s = 0; s < 32; ++s) mx = fmaxf(mx, S[base + s]);
      mx = fmaxf(mx, __shfl_xor(mx, 1));
      mx = fmaxf(mx, __shfl_xor(mx, 2));
      float sm = 0.f;
      for (int s = 0; s < 32; ++s) {
        float ev = expf((S[base + s] - mx) * scale);
        S[base + s] = ev;
        sm += ev;
      }
      sm += __shfl_xor(sm, 1);
      sm += __shfl_xor(sm, 2);
      float inv = 1.f / sm;
      for (int s = 0; s < 32; ++s) S[base + s] *= inv;
    }
    __syncthreads();

    // accumulate column mean of P (mean over l follows through PV)
    if (tid < 128) {
      float s = 0.f;
      for (int l = 0; l < 64; ++l) s += S[l * 129 + tid];
      pbar[tid] += s * (1.f / 128.f);
    }
  }
  __syncthreads();

  // ctx[d] = sum_m pbar[m] * V[b,m,d]
  float ctx[3];
  const float* vbase = Vb + (size_t)b * 128 * D;
#pragma unroll
  for (int r = 0; r < 3; ++r) {
    int d = tid + r * 256;
    float a = 0.f;
    for (int m = 0; m < 128; ++m) a += pbar[m] * vbase[(size_t)m * D + d];
    ctx[r] = a;
  }

  // LayerNorm over d
  float ps = ctx[0] + ctx[1] + ctx[2];
  float mu = blockSum(ps, red, tid) * (1.f / 768.f);
  float vs = 0.f;
#pragma unroll
  for (int r = 0; r < 3; ++r) { float c = ctx[r] - mu; vs += c * c; }
  float var = blockSum(vs, red, tid) * (1.f / 768.f);
  float rstd = rsqrtf(var + 1e-5f);

  // final dots
  const float* eclsm = MOE + (size_t)(n * 129) * D; // ent_cls_moe row
  float g2l_p = 0.f, g2g_p = 0.f;
#pragma unroll
  for (int r = 0; r < 3; ++r) {
    int d = tid + r * 256;
    float cl = (ctx[r] - mu) * rstd * ln_w[d] + ln_b[d];
    g2l_p += eclsm[d] * cl;
    g2g_p += mcls[(size_t)b * D + d] * ecls[(size_t)n * D + d];
  }
  float g2l = blockSum(g2l_p, red, tid);
  float g2g = blockSum(g2g_p, red, tid);
  if (tid == 0) out[b * 32 + n] = 0.5f * (g2l + g2g);
}

extern "C" void kernel_launch(void* const* d_in, const int* in_sizes, int n_in,
                              void* d_out, int out_size, void* d_ws, size_t ws_size,
                              hipStream_t stream) {
  const float* ecls   = (const float*)d_in[0];
  const float* etok   = (const float*)d_in[1];
  const float* mcls   = (const float*)d_in[2];
  const float* mtok   = (const float*)d_in[3];
  const float* gate_w = (const float*)d_in[4];
  const float* gate_b = (const float*)d_in[5];
  const float* exp_w  = (const float*)d_in[6];
  const float* exp_b  = (const float*)d_in[7];
  const float* wq     = (const float*)d_in[8];
  const float* bq     = (const float*)d_in[9];
  const float* wk     = (const float*)d_in[10];
  const float* bk     = (const float*)d_in[11];
  const float* wv     = (const float*)d_in[12];
  const float* bv     = (const float*)d_in[13];
  const float* ln_w   = (const float*)d_in[14];
  const float* ln_b   = (const float*)d_in[15];
  float* outp = (float*)d_out;

  // workspace layout (floats)
  float* MOE = (float*)d_ws;                    // 6192*768
  float* Q   = MOE + (size_t)NTOK * D;          // 4096*768
  float* K   = Q + (size_t)4096 * D;            // 2048*768
  float* V   = K + (size_t)2048 * D;            // 2048*768
  int*   cnt = (int*)(V + (size_t)2048 * D);    // 8
  int*   lst_idx = cnt + 8;                     // 8*6192
  float* lst_w = (float*)(lst_idx + NE * LISTCAP);

  hipMemsetAsync(cnt, 0, NE * sizeof(int), stream);
  hipMemsetAsync(MOE, 0, (size_t)NTOK * D * sizeof(float), stream);

  gate_kernel<<<NTOK / 4, 256, 0, stream>>>(ecls, etok, mcls, mtok, gate_w, gate_b,
                                            cnt, lst_idx, lst_w);
  moe_expert_kernel<<<dim3(97, 12, 8), 256, 0, stream>>>(ecls, etok, mcls, mtok,
                                                         exp_w, exp_b, cnt, lst_idx, lst_w, MOE);
  qkv_kernel<<<dim3(64, 12, 3), 256, 0, stream>>>(MOE, wq, bq, wk, bk, wv, bv, Q, K, V);
  attn_kernel<<<dim3(16, 32), 256, 0, stream>>>(Q, K, V, MOE, ecls, mcls, ln_w, ln_b, outp);
}

// Round 2
// 348.550 us; speedup vs baseline: 3.2925x; 3.2925x over previous
//
#include <hip/hip_runtime.h>
#include <math.h>

#define D 768
#define NE 8
#define NTOK 6192      // 32*129 + 16*129
#define MEN_TOK0 4128  // 32*129
#define LISTCAP 6192

typedef __attribute__((ext_vector_type(8))) short short8;   // 8 x bf16
typedef __attribute__((ext_vector_type(4))) float floatx4;  // MFMA C/D

__device__ __forceinline__ short f2bf(float f) {
  union { float f; unsigned u; } x; x.f = f;
  unsigned r = x.u + 0x7fffu + ((x.u >> 16) & 1u);
  return (short)(r >> 16);
}
__device__ __forceinline__ float bf2f(short s) {
  union { unsigned u; float f; } x; x.u = ((unsigned)(unsigned short)s) << 16;
  return x.f;
}

// Map concatenated token index -> source row pointer (virtual concat, no copy).
__device__ __forceinline__ const float* token_row(int t,
    const float* __restrict__ ecls, const float* __restrict__ etok,
    const float* __restrict__ mcls, const float* __restrict__ mtok) {
  if (t < MEN_TOK0) {
    int n = t / 129, s = t - n * 129;
    return (s == 0) ? (ecls + n * D) : (etok + (size_t)(n * 128 + s - 1) * D);
  } else {
    int tm = t - MEN_TOK0;
    int b = tm / 129, s = tm - b * 129;
    return (s == 0) ? (mcls + b * D) : (mtok + (size_t)(b * 128 + s - 1) * D);
  }
}

// ---------------- gate: top-2 of (x @ gate_w + gate_b), build per-expert lists
__global__ __launch_bounds__(256) void gate_kernel(
    const float* __restrict__ ecls, const float* __restrict__ etok,
    const float* __restrict__ mcls, const float* __restrict__ mtok,
    const float* __restrict__ gate_w, const float* __restrict__ gate_b,
    int* __restrict__ cnt, int* __restrict__ lst_idx, float* __restrict__ lst_w) {
  int t = blockIdx.x * 4 + (threadIdx.x >> 6);
  if (t >= NTOK) return;
  int lane = threadIdx.x & 63;
  const float* xr = token_row(t, ecls, etok, mcls, mtok);
  float acc[NE];
#pragma unroll
  for (int e = 0; e < NE; ++e) acc[e] = 0.f;
  for (int d = lane; d < D; d += 64) {
    float xv = xr[d];
#pragma unroll
    for (int e = 0; e < NE; ++e) acc[e] += xv * gate_w[d * NE + e];
  }
#pragma unroll
  for (int e = 0; e < NE; ++e) {
#pragma unroll
    for (int off = 32; off > 0; off >>= 1) acc[e] += __shfl_down(acc[e], off);
  }
  if (lane == 0) {
    float lg[NE];
#pragma unroll
    for (int e = 0; e < NE; ++e) lg[e] = acc[e] + gate_b[e];
    int e1 = 0;
#pragma unroll
    for (int e = 1; e < NE; ++e) if (lg[e] > lg[e1]) e1 = e;
    int e2 = (e1 == 0) ? 1 : 0;
#pragma unroll
    for (int e = 0; e < NE; ++e) {
      if (e != e1 && lg[e] > lg[e2]) e2 = e;
    }
    float w1 = 1.f / (1.f + __expf(lg[e2] - lg[e1]));
    float w2 = 1.f - w1;
    int p1 = atomicAdd(&cnt[e1], 1);
    lst_idx[e1 * LISTCAP + p1] = t;
    lst_w [e1 * LISTCAP + p1] = w1;
    int p2 = atomicAdd(&cnt[e2], 1);
    lst_idx[e2 * LISTCAP + p2] = t;
    lst_w [e2 * LISTCAP + p2] = w2;
  }
}

// ---------------- transpose + fp32->bf16 convert of weight matrices
// z<8: exp_w[z] (k,o) -> expwT[z] (o,k); z=8,9,10: wq/wk/wv -> wT[z-8] (o,k)
__global__ __launch_bounds__(256) void tcvt_kernel(
    const float* __restrict__ exp_w, const float* __restrict__ wq,
    const float* __restrict__ wk, const float* __restrict__ wv,
    short* __restrict__ expwT, short* __restrict__ wT) {
  int z = blockIdx.z;
  const float* src; short* dst;
  if (z < 8) { src = exp_w + (size_t)z * D * D; dst = expwT + (size_t)z * D * D; }
  else { src = (z == 8) ? wq : (z == 9) ? wk : wv; dst = wT + (size_t)(z - 8) * D * D; }
  int k0 = blockIdx.x * 64, o0 = blockIdx.y * 64;
  __shared__ float t[64][65];
  int tid = threadIdx.x;
  int tx = tid & 63, ty = tid >> 6;
#pragma unroll
  for (int i = 0; i < 16; ++i) {
    int k = i * 4 + ty;
    t[k][tx] = src[(size_t)(k0 + k) * D + o0 + tx];
  }
  __syncthreads();
#pragma unroll
  for (int i = 0; i < 16; ++i) {
    int o = i * 4 + ty;
    dst[(size_t)(o0 + o) * D + k0 + tx] = f2bf(t[tx][o]);
  }
}

// ---------------- grouped expert GEMM (MFMA bf16): MOE[t,:] += w*(x_t @ W_e + b_e)
__global__ __launch_bounds__(256) void moe_kernel(
    const float* __restrict__ ecls, const float* __restrict__ etok,
    const float* __restrict__ mcls, const float* __restrict__ mtok,
    const short* __restrict__ expwT, const float* __restrict__ exp_b,
    const int* __restrict__ cnt, const int* __restrict__ lst_idx,
    const float* __restrict__ lst_w, float* __restrict__ MOE) {
  int e = blockIdx.z;
  int count = cnt[e];
  int t0 = blockIdx.x * 64;
  if (t0 >= count) return;
  int o0 = blockIdx.y * 128;

  __shared__ short8 As[512];    // 64 rows x 8 chunks (64 bf16), XOR-swizzled
  __shared__ short8 Bs[1024];   // 128 rows x 8 chunks
  __shared__ const float* sptr[64];
  __shared__ int stok[64];
  __shared__ float swt[64];

  int tid = threadIdx.x;
  int l = tid & 63, w = tid >> 6;
  if (tid < 64) {
    int p = t0 + tid;
    int tok = 0; float wt = 0.f;
    if (p < count) { tok = lst_idx[e * LISTCAP + p]; wt = lst_w[e * LISTCAP + p]; }
    stok[tid] = tok; swt[tid] = wt;
    sptr[tid] = token_row(tok, ecls, etok, mcls, mtok);
  }

  floatx4 acc[8];
#pragma unroll
  for (int j = 0; j < 8; ++j) acc[j] = (floatx4){0.f, 0.f, 0.f, 0.f};

  const short* Bg = expwT + (size_t)e * D * D;

  for (int k0 = 0; k0 < D; k0 += 64) {
    __syncthreads();
    // stage A: gathered fp32 rows -> bf16 LDS tile
#pragma unroll
    for (int q = 0; q < 2; ++q) {
      int p = q * 256 + tid;
      int row = p >> 3, c = p & 7;
      const float* s = sptr[row] + k0 + c * 8;
      floatx4 f0 = *(const floatx4*)(s);
      floatx4 f1 = *(const floatx4*)(s + 4);
      short8 v;
#pragma unroll
      for (int t = 0; t < 4; ++t) { v[t] = f2bf(f0[t]); v[t + 4] = f2bf(f1[t]); }
      As[(row << 3) + (c ^ (row & 7))] = v;
    }
    // stage B: expwT rows (o-major)
#pragma unroll
    for (int q = 0; q < 4; ++q) {
      int p = q * 256 + tid;
      int row = p >> 3, c = p & 7;
      Bs[(row << 3) + (c ^ (row & 7))] =
          *(const short8*)(Bg + (size_t)(o0 + row) * D + k0 + c * 8);
    }
    __syncthreads();
#pragma unroll
    for (int kk = 0; kk < 2; ++kk) {
      int kc = kk * 4 + (l >> 4);
      int ar = w * 16 + (l & 15);
      short8 a = As[(ar << 3) + (kc ^ (ar & 7))];
#pragma unroll
      for (int j = 0; j < 8; ++j) {
        int br = j * 16 + (l & 15);
        short8 bb = Bs[(br << 3) + (kc ^ (br & 7))];
        acc[j] = __builtin_amdgcn_mfma_f32_16x16x32_bf16(a, bb, acc[j], 0, 0, 0);
      }
    }
  }

  // epilogue: C/D layout col=lane&15, row=(lane>>4)*4+reg
  int rbase = w * 16 + ((l >> 4) << 2);
#pragma unroll
  for (int r = 0; r < 4; ++r) {
    int rl = rbase + r;
    float wt = swt[rl];
    if (wt != 0.f) {
      int tok = stok[rl];
#pragma unroll
      for (int j = 0; j < 8; ++j) {
        int col = o0 + j * 16 + (l & 15);
        atomicAdd(&MOE[(size_t)tok * D + col], wt * (acc[j][r] + exp_b[e * D + col]));
      }
    }
  }
}

// ---------------- elementwise convert MOE fp32 -> bf16
__global__ __launch_bounds__(256) void cvt_moe_kernel(
    const float* __restrict__ MOE, short* __restrict__ MOEb) {
  size_t i = ((size_t)blockIdx.x * 256 + threadIdx.x) * 8;
  floatx4 f0 = *(const floatx4*)(MOE + i);
  floatx4 f1 = *(const floatx4*)(MOE + i + 4);
  short8 v;
#pragma unroll
  for (int t = 0; t < 4; ++t) { v[t] = f2bf(f0[t]); v[t + 4] = f2bf(f1[t]); }
  *(short8*)(MOEb + i) = v;
}

// ---------------- QKV projections (MFMA bf16). z=0:Q(4096 rows) z=1:K z=2:V
__global__ __launch_bounds__(256) void qkv_kernel(
    const short* __restrict__ MOEb, const short* __restrict__ wT,
    const float* __restrict__ bq, const float* __restrict__ bk,
    const float* __restrict__ bv,
    short* __restrict__ Qb, short* __restrict__ Kb, float* __restrict__ V) {
  int z = blockIdx.z;
  int nrows = (z == 0) ? 4096 : 2048;
  int r0 = blockIdx.x * 64;
  if (r0 >= nrows) return;
  int o0 = blockIdx.y * 128;
  int base = (z == 0) ? 0 : MEN_TOK0;
  const short* W = wT + (size_t)z * D * D;
  const float* bias = (z == 0) ? bq : (z == 1) ? bk : bv;

  __shared__ short8 As[512];
  __shared__ short8 Bs[1024];
  int tid = threadIdx.x;
  int l = tid & 63, w = tid >> 6;
  floatx4 acc[8];
#pragma unroll
  for (int j = 0; j < 8; ++j) acc[j] = (floatx4){0.f, 0.f, 0.f, 0.f};

  for (int k0 = 0; k0 < D; k0 += 64) {
    __syncthreads();
#pragma unroll
    for (int q = 0; q < 2; ++q) {
      int p = q * 256 + tid;
      int row = p >> 3, c = p & 7;
      int r = r0 + row;
      int mrow = base + (r >> 7) * 129 + 1 + (r & 127);
      As[(row << 3) + (c ^ (row & 7))] =
          *(const short8*)(MOEb + (size_t)mrow * D + k0 + c * 8);
    }
#pragma unroll
    for (int q = 0; q < 4; ++q) {
      int p = q * 256 + tid;
      int row = p >> 3, c = p & 7;
      Bs[(row << 3) + (c ^ (row & 7))] =
          *(const short8*)(W + (size_t)(o0 + row) * D + k0 + c * 8);
    }
    __syncthreads();
#pragma unroll
    for (int kk = 0; kk < 2; ++kk) {
      int kc = kk * 4 + (l >> 4);
      int ar = w * 16 + (l & 15);
      short8 a = As[(ar << 3) + (kc ^ (ar & 7))];
#pragma unroll
      for (int j = 0; j < 8; ++j) {
        int br = j * 16 + (l & 15);
        short8 bb = Bs[(br << 3) + (kc ^ (br & 7))];
        acc[j] = __builtin_amdgcn_mfma_f32_16x16x32_bf16(a, bb, acc[j], 0, 0, 0);
      }
    }
  }

  int rbase = w * 16 + ((l >> 4) << 2);
#pragma unroll
  for (int r = 0; r < 4; ++r) {
    int rr = r0 + rbase + r;
#pragma unroll
    for (int j = 0; j < 8; ++j) {
      int col = o0 + j * 16 + (l & 15);
      float v = acc[j][r] + bias[col];
      if (z == 0)      Qb[(size_t)rr * D + col] = f2bf(v);
      else if (z == 1) Kb[(size_t)rr * D + col] = f2bf(v);
      else             V [(size_t)rr * D + col] = v;
    }
  }
}

// ---------------- fused scores GEMM (MFMA) + in-register softmax + column-mean
// block (b,n): S = Q_n (128x768) . K_b^T -> softmax rows -> pbar[m] = mean_l P
__global__ __launch_bounds__(256) void attn_kernel(
    const short* __restrict__ Qb, const short* __restrict__ Kb,
    float* __restrict__ pbar_ws) {
  int b = blockIdx.x, n = blockIdx.y;
  __shared__ short8 Qs[1024];   // 128 rows x 8 chunks, swizzled
  __shared__ short8 Ks[1024];
  __shared__ float pb[128];
  int tid = threadIdx.x;
  int l = tid & 63, w = tid >> 6;
  if (tid < 128) pb[tid] = 0.f;

  floatx4 acc[2][8];
#pragma unroll
  for (int i = 0; i < 2; ++i)
#pragma unroll
    for (int j = 0; j < 8; ++j) acc[i][j] = (floatx4){0.f, 0.f, 0.f, 0.f};

  const short* qg = Qb + (size_t)n * 128 * D;
  const short* kg = Kb + (size_t)b * 128 * D;

  for (int k0 = 0; k0 < D; k0 += 64) {
    __syncthreads();
#pragma unroll
    for (int q = 0; q < 4; ++q) {
      int p = q * 256 + tid;
      int row = p >> 3, c = p & 7;
      int sw = (row << 3) + (c ^ (row & 7));
      Qs[sw] = *(const short8*)(qg + (size_t)row * D + k0 + c * 8);
      Ks[sw] = *(const short8*)(kg + (size_t)row * D + k0 + c * 8);
    }
    __syncthreads();
#pragma unroll
    for (int kk = 0; kk < 2; ++kk) {
      int kc = kk * 4 + (l >> 4);
      short8 a[2], bb[8];
#pragma unroll
      for (int i = 0; i < 2; ++i) {
        int ar = w * 32 + i * 16 + (l & 15);
        a[i] = Qs[(ar << 3) + (kc ^ (ar & 7))];
      }
#pragma unroll
      for (int j = 0; j < 8; ++j) {
        int br = j * 16 + (l & 15);
        bb[j] = Ks[(br << 3) + (kc ^ (br & 7))];
      }
#pragma unroll
      for (int i = 0; i < 2; ++i)
#pragma unroll
        for (int j = 0; j < 8; ++j)
          acc[i][j] = __builtin_amdgcn_mfma_f32_16x16x32_bf16(a[i], bb[j], acc[i][j], 0, 0, 0);
    }
  }

  const float scale = 0.03608439182435161f; // 1/sqrt(768)
  float colsum[8];
#pragma unroll
  for (int j = 0; j < 8; ++j) colsum[j] = 0.f;

#pragma unroll
  for (int i = 0; i < 2; ++i) {
#pragma unroll
    for (int r = 0; r < 4; ++r) {
      // row = w*32 + i*16 + (l>>4)*4 + r ; cols j*16+(l&15) live across low-4 lane bits
      float mx = -3.0e38f;
#pragma unroll
      for (int j = 0; j < 8; ++j) mx = fmaxf(mx, acc[i][j][r]);
      mx = fmaxf(mx, __shfl_xor(mx, 1));
      mx = fmaxf(mx, __shfl_xor(mx, 2));
      mx = fmaxf(mx, __shfl_xor(mx, 4));
      mx = fmaxf(mx, __shfl_xor(mx, 8));
      float pv[8], sm = 0.f;
#pragma unroll
      for (int j = 0; j < 8; ++j) { pv[j] = __expf((acc[i][j][r] - mx) * scale); sm += pv[j]; }
      sm += __shfl_xor(sm, 1);
      sm += __shfl_xor(sm, 2);
      sm += __shfl_xor(sm, 4);
      sm += __shfl_xor(sm, 8);
      float inv = 1.f / sm;
#pragma unroll
      for (int j = 0; j < 8; ++j) colsum[j] += pv[j] * inv;
    }
  }
#pragma unroll
  for (int j = 0; j < 8; ++j) {
    colsum[j] += __shfl_xor(colsum[j], 16);
    colsum[j] += __shfl_xor(colsum[j], 32);
  }
  if (l < 16) {
#pragma unroll
    for (int j = 0; j < 8; ++j) atomicAdd(&pb[j * 16 + l], colsum[j]);
  }
  __syncthreads();
  if (tid < 128) pbar_ws[((size_t)n * 16 + b) * 128 + tid] = pb[tid] * (1.f / 128.f);
}

// ---------------- ctx[b,n,d] = sum_m pbar[n,b,m] * V[b,m,d]  (V read once)
__global__ __launch_bounds__(256) void pv_kernel(
    const float* __restrict__ pbar_ws, const float* __restrict__ V,
    float* __restrict__ CTX) {
  int b = blockIdx.x, dc = blockIdx.y;
  __shared__ float pbs[4096];   // [n][m]
  int tid = threadIdx.x;
#pragma unroll
  for (int i = 0; i < 16; ++i) {
    int idx = i * 256 + tid;
    int nn = idx >> 7, m = idx & 127;
    pbs[idx] = pbar_ws[((size_t)nn * 16 + b) * 128 + m];
  }
  __syncthreads();
  int d = dc * 256 + tid;
  float acc[32];
#pragma unroll
  for (int nn = 0; nn < 32; ++nn) acc[nn] = 0.f;
  const float* vb = V + (size_t)b * 128 * D + d;
  for (int m = 0; m < 128; ++m) {
    float v = vb[(size_t)m * D];
#pragma unroll
    for (int nn = 0; nn < 32; ++nn) acc[nn] += pbs[nn * 128 + m] * v;
  }
#pragma unroll
  for (int nn = 0; nn < 32; ++nn) CTX[((size_t)b * 32 + nn) * D + d] = acc[nn];
}

__device__ __forceinline__ float blockSum(float v, volatile float* red, int tid) {
#pragma unroll
  for (int off = 32; off > 0; off >>= 1) v += __shfl_down(v, off);
  __syncthreads();
  if ((tid & 63) == 0) red[tid >> 6] = v;
  __syncthreads();
  return red[0] + red[1] + red[2] + red[3];
}

// ---------------- LayerNorm + final dots
__global__ __launch_bounds__(256) void ln_dot_kernel(
    const float* __restrict__ CTX, const short* __restrict__ MOEb,
    const float* __restrict__ ecls, const float* __restrict__ mcls,
    const float* __restrict__ ln_w, const float* __restrict__ ln_b,
    float* __restrict__ out) {
  __shared__ float red[4];
  int bn = blockIdx.x;
  int b = bn >> 5, n = bn & 31;
  int tid = threadIdx.x;
  const float* cr = CTX + (size_t)bn * D;
  float ctx[3];
#pragma unroll
  for (int r = 0; r < 3; ++r) ctx[r] = cr[tid + r * 256];
  float mu = blockSum(ctx[0] + ctx[1] + ctx[2], red, tid) * (1.f / 768.f);
  float vs = 0.f;
#pragma unroll
  for (int r = 0; r < 3; ++r) { float c = ctx[r] - mu; vs += c * c; }
  float var = blockSum(vs, red, tid) * (1.f / 768.f);
  float rstd = rsqrtf(var + 1e-5f);
  const short* em = MOEb + (size_t)(n * 129) * D;
  float g2l_p = 0.f, g2g_p = 0.f;
#pragma unroll
  for (int r = 0; r < 3; ++r) {
    int d = tid + r * 256;
    float cl = (ctx[r] - mu) * rstd * ln_w[d] + ln_b[d];
    g2l_p += bf2f(em[d]) * cl;
    g2g_p += mcls[(size_t)b * D + d] * ecls[(size_t)n * D + d];
  }
  float g2l = blockSum(g2l_p, red, tid);
  float g2g = blockSum(g2g_p, red, tid);
  if (tid == 0) out[bn] = 0.5f * (g2l + g2g);
}

extern "C" void kernel_launch(void* const* d_in, const int* in_sizes, int n_in,
                              void* d_out, int out_size, void* d_ws, size_t ws_size,
                              hipStream_t stream) {
  const float* ecls   = (const float*)d_in[0];
  const float* etok   = (const float*)d_in[1];
  const float* mcls   = (const float*)d_in[2];
  const float* mtok   = (const float*)d_in[3];
  const float* gate_w = (const float*)d_in[4];
  const float* gate_b = (const float*)d_in[5];
  const float* exp_w  = (const float*)d_in[6];
  const float* exp_b  = (const float*)d_in[7];
  const float* wq     = (const float*)d_in[8];
  const float* bq     = (const float*)d_in[9];
  const float* wk     = (const float*)d_in[10];
  const float* bk     = (const float*)d_in[11];
  const float* wv     = (const float*)d_in[12];
  const float* bv     = (const float*)d_in[13];
  const float* ln_w   = (const float*)d_in[14];
  const float* ln_b   = (const float*)d_in[15];
  float* outp = (float*)d_out;

  char* ws = (char*)d_ws;
  // phase-1 region (fp32 MOE), later reused for Qb/Kb/V
  float* MOE   = (float*)(ws + 0);              // 19,021,824 B
  short* Qb    = (short*)(ws + 0);              //  6,291,456 B (after cvt)
  short* Kb    = (short*)(ws + 6291456);        //  3,145,728 B
  float* V     = (float*)(ws + 9437184);        //  6,291,456 B (ends 15,728,640)
  short* MOEb  = (short*)(ws + 19021824);       //  9,510,912 B
  short* expwT = (short*)(ws + 28532736);       //  9,437,184 B
  short* wT    = (short*)(ws + 37969920);       //  3,538,944 B
  float* PBAR  = (float*)(ws + 41508864);       //    262,144 B
  float* CTX   = (float*)(ws + 41771008);       //  1,572,864 B
  int*   cnt   = (int*)  (ws + 43343872);       //         32 B
  int*   lidx  = (int*)  (ws + 43343904);       //    198,144 B
  float* lw    = (float*)(ws + 43542048);       //    198,144 B  (total 43,740,192)

  hipMemsetAsync(cnt, 0, 32, stream);
  hipMemsetAsync(MOE, 0, (size_t)NTOK * D * sizeof(float), stream);

  gate_kernel<<<NTOK / 4, 256, 0, stream>>>(ecls, etok, mcls, mtok, gate_w, gate_b,
                                            cnt, lidx, lw);
  tcvt_kernel<<<dim3(12, 12, 11), 256, 0, stream>>>(exp_w, wq, wk, wv, expwT, wT);
  moe_kernel<<<dim3(97, 6, 8), 256, 0, stream>>>(ecls, etok, mcls, mtok,
                                                 expwT, exp_b, cnt, lidx, lw, MOE);
  cvt_moe_kernel<<<2322, 256, 0, stream>>>(MOE, MOEb);
  qkv_kernel<<<dim3(64, 6, 3), 256, 0, stream>>>(MOEb, wT, bq, bk, bv, Qb, Kb, V);
  attn_kernel<<<dim3(16, 32), 256, 0, stream>>>(Qb, Kb, PBAR);
  pv_kernel<<<dim3(16, 3), 256, 0, stream>>>(PBAR, V, CTX);
  ln_dot_kernel<<<512, 256, 0, stream>>>(CTX, MOEb, ecls, mcls, ln_w, ln_b, outp);
}

// Round 3
// 184.254 us; speedup vs baseline: 6.2283x; 1.8917x over previous
//
#include <hip/hip_runtime.h>
#include <math.h>

#define D 768
#define NE 8
#define NTOK 6192      // 32*129 + 16*129
#define MEN_TOK0 4128  // 32*129
#define NSLOT 12384    // 2*NTOK
#define NCBLK 25       // ceil(6192/256)

typedef __attribute__((ext_vector_type(8))) short short8;   // 8 x bf16
typedef __attribute__((ext_vector_type(4))) float floatx4;  // MFMA C/D

__device__ __forceinline__ short f2bf(float f) {
  union { float f; unsigned u; } x; x.f = f;
  unsigned r = x.u + 0x7fffu + ((x.u >> 16) & 1u);
  return (short)(r >> 16);
}
__device__ __forceinline__ float bf2f(short s) {
  union { unsigned u; float f; } x; x.u = ((unsigned)(unsigned short)s) << 16;
  return x.f;
}

// Map concatenated token index -> source row pointer (virtual concat, no copy).
__device__ __forceinline__ const float* token_row(int t,
    const float* __restrict__ ecls, const float* __restrict__ etok,
    const float* __restrict__ mcls, const float* __restrict__ mtok) {
  if (t < MEN_TOK0) {
    int n = t / 129, s = t - n * 129;
    return (s == 0) ? (ecls + n * D) : (etok + (size_t)(n * 128 + s - 1) * D);
  } else {
    int tm = t - MEN_TOK0;
    int b = tm / 129, s = tm - b * 129;
    return (s == 0) ? (mcls + b * D) : (mtok + (size_t)(b * 128 + s - 1) * D);
  }
}

// ---------------- gate logits + top-2 (dense outputs, NO atomics)
__global__ __launch_bounds__(256) void gate_kernel(
    const float* __restrict__ ecls, const float* __restrict__ etok,
    const float* __restrict__ mcls, const float* __restrict__ mtok,
    const float* __restrict__ gate_w, const float* __restrict__ gate_b,
    int* __restrict__ te1, int* __restrict__ te2,
    float* __restrict__ tw1, float* __restrict__ tw2) {
  int t = blockIdx.x * 4 + (threadIdx.x >> 6);
  int lane = threadIdx.x & 63;
  const float* xr = token_row(t, ecls, etok, mcls, mtok);
  float acc[NE];
#pragma unroll
  for (int e = 0; e < NE; ++e) acc[e] = 0.f;
#pragma unroll
  for (int it = 0; it < 3; ++it) {
    int d0 = lane * 4 + it * 256;
    floatx4 x = *(const floatx4*)(xr + d0);
#pragma unroll
    for (int q = 0; q < 4; ++q) {
      float xv = x[q];
#pragma unroll
      for (int e = 0; e < NE; ++e) acc[e] += xv * gate_w[(d0 + q) * NE + e];
    }
  }
#pragma unroll
  for (int e = 0; e < NE; ++e) {
#pragma unroll
    for (int off = 32; off > 0; off >>= 1) acc[e] += __shfl_down(acc[e], off);
  }
  if (lane == 0) {
    float lg[NE];
#pragma unroll
    for (int e = 0; e < NE; ++e) lg[e] = acc[e] + gate_b[e];
    int e1 = 0;
#pragma unroll
    for (int e = 1; e < NE; ++e) if (lg[e] > lg[e1]) e1 = e;
    int e2 = (e1 == 0) ? 1 : 0;
#pragma unroll
    for (int e = 0; e < NE; ++e) {
      if (e != e1 && lg[e] > lg[e2]) e2 = e;
    }
    float w1 = 1.f / (1.f + __expf(lg[e2] - lg[e1]));
    te1[t] = e1; te2[t] = e2;
    tw1[t] = w1; tw2[t] = 1.f - w1;
  }
}

// ---------------- per-block expert histograms (LDS atomics only)
__global__ __launch_bounds__(256) void count_kernel(
    const int* __restrict__ te1, const int* __restrict__ te2,
    int* __restrict__ localcnt) {
  __shared__ int h[NE];
  int tid = threadIdx.x;
  if (tid < NE) h[tid] = 0;
  __syncthreads();
  int t = blockIdx.x * 256 + tid;
  if (t < NTOK) {
    atomicAdd(&h[te1[t]], 1);
    atomicAdd(&h[te2[t]], 1);
  }
  __syncthreads();
  if (tid < NE) localcnt[blockIdx.x * NE + tid] = h[tid];
}

// ---------------- compact: global per-expert-contiguous slot assignment
__global__ __launch_bounds__(256) void compact_kernel(
    const int* __restrict__ te1, const int* __restrict__ te2,
    const int* __restrict__ localcnt,
    int* __restrict__ lst_tok, int* __restrict__ slot1, int* __restrict__ slot2,
    int* __restrict__ cnt, int* __restrict__ basee) {
  __shared__ int lc[NCBLK * NE];
  __shared__ int gbase[NE];
  __shared__ int ctr[NE];
  int tid = threadIdx.x;
  for (int i = tid; i < NCBLK * NE; i += 256) lc[i] = localcnt[i];
  if (tid < NE) ctr[tid] = 0;
  __syncthreads();
  if (tid < NE) {
    int e = tid;
    int mytotal = 0, myblockpre = 0;
    for (int j = 0; j < NCBLK; ++j) {
      int v = lc[j * NE + e];
      mytotal += v;
      if (j < (int)blockIdx.x) myblockpre += v;
    }
    int eb = 0;
    for (int ep = 0; ep < e; ++ep) {
      int tt = 0;
      for (int j = 0; j < NCBLK; ++j) tt += lc[j * NE + ep];
      eb += tt;
    }
    gbase[e] = eb + myblockpre;
    if (blockIdx.x == 0) { cnt[e] = mytotal; basee[e] = eb; }
  }
  __syncthreads();
  int t = blockIdx.x * 256 + tid;
  if (t < NTOK) {
    int e1 = te1[t], e2 = te2[t];
    int r1 = atomicAdd(&ctr[e1], 1);
    int r2 = atomicAdd(&ctr[e2], 1);
    int s1 = gbase[e1] + r1;
    int s2 = gbase[e2] + r2;
    slot1[t] = s1; slot2[t] = s2;
    lst_tok[s1] = t; lst_tok[s2] = t;
  }
}

// ---------------- transpose + fp32->bf16 convert of weight matrices
// z<8: exp_w[z] (k,o) -> expwT[z] (o,k); z=8,9,10: wq/wk/wv -> wT[z-8] (o,k)
__global__ __launch_bounds__(256) void tcvt_kernel(
    const float* __restrict__ exp_w, const float* __restrict__ wq,
    const float* __restrict__ wk, const float* __restrict__ wv,
    short* __restrict__ expwT, short* __restrict__ wT) {
  int z = blockIdx.z;
  const float* src; short* dst;
  if (z < 8) { src = exp_w + (size_t)z * D * D; dst = expwT + (size_t)z * D * D; }
  else { src = (z == 8) ? wq : (z == 9) ? wk : wv; dst = wT + (size_t)(z - 8) * D * D; }
  int k0 = blockIdx.x * 64, o0 = blockIdx.y * 64;
  __shared__ float t[64][65];
  int tid = threadIdx.x;
  int tx = tid & 63, ty = tid >> 6;
#pragma unroll
  for (int i = 0; i < 16; ++i) {
    int k = i * 4 + ty;
    t[k][tx] = src[(size_t)(k0 + k) * D + o0 + tx];
  }
  __syncthreads();
#pragma unroll
  for (int i = 0; i < 16; ++i) {
    int o = i * 4 + ty;
    dst[(size_t)(o0 + o) * D + k0 + tx] = f2bf(t[tx][o]);
  }
}

// ---------------- grouped expert GEMM (MFMA bf16): EO[slot,:] = x_tok @ W_e
__global__ __launch_bounds__(256) void moe_kernel(
    const float* __restrict__ ecls, const float* __restrict__ etok,
    const float* __restrict__ mcls, const float* __restrict__ mtok,
    const short* __restrict__ expwT,
    const int* __restrict__ cnt, const int* __restrict__ basee,
    const int* __restrict__ lst_tok, short* __restrict__ EO) {
  int e = blockIdx.z;
  int count = cnt[e];
  int t0 = blockIdx.x * 64;
  if (t0 >= count) return;
  int o0 = blockIdx.y * 128;
  int gb = basee[e];

  __shared__ short8 As[512];    // 64 rows x 8 chunks (64 bf16), XOR-swizzled
  __shared__ short8 Bs[1024];   // 128 rows x 8 chunks
  __shared__ const float* sptr[64];

  int tid = threadIdx.x;
  int l = tid & 63, w = tid >> 6;
  if (tid < 64) {
    int p = t0 + tid;
    int tok = (p < count) ? lst_tok[gb + p] : lst_tok[gb];
    sptr[tid] = token_row(tok, ecls, etok, mcls, mtok);
  }

  floatx4 acc[8];
#pragma unroll
  for (int j = 0; j < 8; ++j) acc[j] = (floatx4){0.f, 0.f, 0.f, 0.f};

  const short* Bg = expwT + (size_t)e * D * D;

  for (int k0 = 0; k0 < D; k0 += 64) {
    __syncthreads();
#pragma unroll
    for (int q = 0; q < 2; ++q) {
      int p = q * 256 + tid;
      int row = p >> 3, c = p & 7;
      const float* s = sptr[row] + k0 + c * 8;
      floatx4 f0 = *(const floatx4*)(s);
      floatx4 f1 = *(const floatx4*)(s + 4);
      short8 v;
#pragma unroll
      for (int t = 0; t < 4; ++t) { v[t] = f2bf(f0[t]); v[t + 4] = f2bf(f1[t]); }
      As[(row << 3) + (c ^ (row & 7))] = v;
    }
#pragma unroll
    for (int q = 0; q < 4; ++q) {
      int p = q * 256 + tid;
      int row = p >> 3, c = p & 7;
      Bs[(row << 3) + (c ^ (row & 7))] =
          *(const short8*)(Bg + (size_t)(o0 + row) * D + k0 + c * 8);
    }
    __syncthreads();
#pragma unroll
    for (int kk = 0; kk < 2; ++kk) {
      int kc = kk * 4 + (l >> 4);
      int ar = w * 16 + (l & 15);
      short8 a = As[(ar << 3) + (kc ^ (ar & 7))];
#pragma unroll
      for (int j = 0; j < 8; ++j) {
        int br = j * 16 + (l & 15);
        short8 bb = Bs[(br << 3) + (kc ^ (br & 7))];
        acc[j] = __builtin_amdgcn_mfma_f32_16x16x32_bf16(a, bb, acc[j], 0, 0, 0);
      }
    }
  }

  // epilogue: C/D layout col=lane&15, row=(lane>>4)*4+reg; guard padding rows
  int rbase = w * 16 + ((l >> 4) << 2);
#pragma unroll
  for (int r = 0; r < 4; ++r) {
    int p = t0 + rbase + r;
    if (p < count) {
      size_t rowoff = (size_t)(gb + p) * D;
#pragma unroll
      for (int j = 0; j < 8; ++j) {
        int col = o0 + j * 16 + (l & 15);
        EO[rowoff + col] = f2bf(acc[j][r]);
      }
    }
  }
}

// ---------------- combine: MOEb[t] = w1*(EO[s1]+b_e1) + w2*(EO[s2]+b_e2)
__global__ __launch_bounds__(256) void combine_kernel(
    const short* __restrict__ EO,
    const int* __restrict__ te1, const int* __restrict__ te2,
    const float* __restrict__ tw1, const float* __restrict__ tw2,
    const int* __restrict__ slot1, const int* __restrict__ slot2,
    const float* __restrict__ exp_b, short* __restrict__ MOEb) {
  int idx = blockIdx.x * 256 + threadIdx.x;   // 6192*96 total
  int t = idx / 96, cg = idx - t * 96;
  int c0 = cg * 8;
  int e1 = te1[t], e2 = te2[t];
  float w1 = tw1[t], w2 = tw2[t];
  short8 a = *(const short8*)(EO + (size_t)slot1[t] * D + c0);
  short8 b = *(const short8*)(EO + (size_t)slot2[t] * D + c0);
  const float* b1 = exp_b + e1 * D + c0;
  const float* b2 = exp_b + e2 * D + c0;
  short8 o;
#pragma unroll
  for (int j = 0; j < 8; ++j)
    o[j] = f2bf(w1 * (bf2f(a[j]) + b1[j]) + w2 * (bf2f(b[j]) + b2[j]));
  *(short8*)(MOEb + (size_t)t * D + c0) = o;
}

// ---------------- QKV projections (MFMA bf16). z=0:Q(4096 rows) z=1:K z=2:V
__global__ __launch_bounds__(256) void qkv_kernel(
    const short* __restrict__ MOEb, const short* __restrict__ wT,
    const float* __restrict__ bq, const float* __restrict__ bk,
    const float* __restrict__ bv,
    short* __restrict__ Qb, short* __restrict__ Kb, float* __restrict__ V) {
  int z = blockIdx.z;
  int nrows = (z == 0) ? 4096 : 2048;
  int r0 = blockIdx.x * 64;
  if (r0 >= nrows) return;
  int o0 = blockIdx.y * 128;
  int base = (z == 0) ? 0 : MEN_TOK0;
  const short* W = wT + (size_t)z * D * D;
  const float* bias = (z == 0) ? bq : (z == 1) ? bk : bv;

  __shared__ short8 As[512];
  __shared__ short8 Bs[1024];
  int tid = threadIdx.x;
  int l = tid & 63, w = tid >> 6;
  floatx4 acc[8];
#pragma unroll
  for (int j = 0; j < 8; ++j) acc[j] = (floatx4){0.f, 0.f, 0.f, 0.f};

  for (int k0 = 0; k0 < D; k0 += 64) {
    __syncthreads();
#pragma unroll
    for (int q = 0; q < 2; ++q) {
      int p = q * 256 + tid;
      int row = p >> 3, c = p & 7;
      int r = r0 + row;
      int mrow = base + (r >> 7) * 129 + 1 + (r & 127);
      As[(row << 3) + (c ^ (row & 7))] =
          *(const short8*)(MOEb + (size_t)mrow * D + k0 + c * 8);
    }
#pragma unroll
    for (int q = 0; q < 4; ++q) {
      int p = q * 256 + tid;
      int row = p >> 3, c = p & 7;
      Bs[(row << 3) + (c ^ (row & 7))] =
          *(const short8*)(W + (size_t)(o0 + row) * D + k0 + c * 8);
    }
    __syncthreads();
#pragma unroll
    for (int kk = 0; kk < 2; ++kk) {
      int kc = kk * 4 + (l >> 4);
      int ar = w * 16 + (l & 15);
      short8 a = As[(ar << 3) + (kc ^ (ar & 7))];
#pragma unroll
      for (int j = 0; j < 8; ++j) {
        int br = j * 16 + (l & 15);
        short8 bb = Bs[(br << 3) + (kc ^ (br & 7))];
        acc[j] = __builtin_amdgcn_mfma_f32_16x16x32_bf16(a, bb, acc[j], 0, 0, 0);
      }
    }
  }

  int rbase = w * 16 + ((l >> 4) << 2);
#pragma unroll
  for (int r = 0; r < 4; ++r) {
    int rr = r0 + rbase + r;
#pragma unroll
    for (int j = 0; j < 8; ++j) {
      int col = o0 + j * 16 + (l & 15);
      float v = acc[j][r] + bias[col];
      if (z == 0)      Qb[(size_t)rr * D + col] = f2bf(v);
      else if (z == 1) Kb[(size_t)rr * D + col] = f2bf(v);
      else             V [(size_t)rr * D + col] = v;
    }
  }
}

// ---------------- fused scores GEMM (MFMA) + in-register softmax + column-mean
__global__ __launch_bounds__(256) void attn_kernel(
    const short* __restrict__ Qb, const short* __restrict__ Kb,
    float* __restrict__ pbar_ws) {
  int b = blockIdx.x, n = blockIdx.y;
  __shared__ short8 Qs[1024];   // 128 rows x 8 chunks, swizzled
  __shared__ short8 Ks[1024];
  __shared__ float pb[128];
  int tid = threadIdx.x;
  int l = tid & 63, w = tid >> 6;
  if (tid < 128) pb[tid] = 0.f;

  floatx4 acc[2][8];
#pragma unroll
  for (int i = 0; i < 2; ++i)
#pragma unroll
    for (int j = 0; j < 8; ++j) acc[i][j] = (floatx4){0.f, 0.f, 0.f, 0.f};

  const short* qg = Qb + (size_t)n * 128 * D;
  const short* kg = Kb + (size_t)b * 128 * D;

  for (int k0 = 0; k0 < D; k0 += 64) {
    __syncthreads();
#pragma unroll
    for (int q = 0; q < 4; ++q) {
      int p = q * 256 + tid;
      int row = p >> 3, c = p & 7;
      int sw = (row << 3) + (c ^ (row & 7));
      Qs[sw] = *(const short8*)(qg + (size_t)row * D + k0 + c * 8);
      Ks[sw] = *(const short8*)(kg + (size_t)row * D + k0 + c * 8);
    }
    __syncthreads();
#pragma unroll
    for (int kk = 0; kk < 2; ++kk) {
      int kc = kk * 4 + (l >> 4);
      short8 a[2], bb[8];
#pragma unroll
      for (int i = 0; i < 2; ++i) {
        int ar = w * 32 + i * 16 + (l & 15);
        a[i] = Qs[(ar << 3) + (kc ^ (ar & 7))];
      }
#pragma unroll
      for (int j = 0; j < 8; ++j) {
        int br = j * 16 + (l & 15);
        bb[j] = Ks[(br << 3) + (kc ^ (br & 7))];
      }
#pragma unroll
      for (int i = 0; i < 2; ++i)
#pragma unroll
        for (int j = 0; j < 8; ++j)
          acc[i][j] = __builtin_amdgcn_mfma_f32_16x16x32_bf16(a[i], bb[j], acc[i][j], 0, 0, 0);
    }
  }

  const float scale = 0.03608439182435161f; // 1/sqrt(768)
  float colsum[8];
#pragma unroll
  for (int j = 0; j < 8; ++j) colsum[j] = 0.f;

#pragma unroll
  for (int i = 0; i < 2; ++i) {
#pragma unroll
    for (int r = 0; r < 4; ++r) {
      float mx = -3.0e38f;
#pragma unroll
      for (int j = 0; j < 8; ++j) mx = fmaxf(mx, acc[i][j][r]);
      mx = fmaxf(mx, __shfl_xor(mx, 1));
      mx = fmaxf(mx, __shfl_xor(mx, 2));
      mx = fmaxf(mx, __shfl_xor(mx, 4));
      mx = fmaxf(mx, __shfl_xor(mx, 8));
      float pv[8], sm = 0.f;
#pragma unroll
      for (int j = 0; j < 8; ++j) { pv[j] = __expf((acc[i][j][r] - mx) * scale); sm += pv[j]; }
      sm += __shfl_xor(sm, 1);
      sm += __shfl_xor(sm, 2);
      sm += __shfl_xor(sm, 4);
      sm += __shfl_xor(sm, 8);
      float inv = 1.f / sm;
#pragma unroll
      for (int j = 0; j < 8; ++j) colsum[j] += pv[j] * inv;
    }
  }
#pragma unroll
  for (int j = 0; j < 8; ++j) {
    colsum[j] += __shfl_xor(colsum[j], 16);
    colsum[j] += __shfl_xor(colsum[j], 32);
  }
  if (l < 16) {
#pragma unroll
    for (int j = 0; j < 8; ++j) atomicAdd(&pb[j * 16 + l], colsum[j]);
  }
  __syncthreads();
  if (tid < 128) pbar_ws[((size_t)n * 16 + b) * 128 + tid] = pb[tid] * (1.f / 128.f);
}

// ---------------- ctx[b,n,d] = sum_m pbar[n,b,m] * V[b,m,d]  (V read once)
__global__ __launch_bounds__(256) void pv_kernel(
    const float* __restrict__ pbar_ws, const float* __restrict__ V,
    float* __restrict__ CTX) {
  int b = blockIdx.x, dc = blockIdx.y;
  __shared__ float pbs[4096];   // [n][m]
  int tid = threadIdx.x;
#pragma unroll
  for (int i = 0; i < 16; ++i) {
    int idx = i * 256 + tid;
    int nn = idx >> 7, m = idx & 127;
    pbs[idx] = pbar_ws[((size_t)nn * 16 + b) * 128 + m];
  }
  __syncthreads();
  int d = dc * 256 + tid;
  float acc[32];
#pragma unroll
  for (int nn = 0; nn < 32; ++nn) acc[nn] = 0.f;
  const float* vb = V + (size_t)b * 128 * D + d;
  for (int m = 0; m < 128; ++m) {
    float v = vb[(size_t)m * D];
#pragma unroll
    for (int nn = 0; nn < 32; ++nn) acc[nn] += pbs[nn * 128 + m] * v;
  }
#pragma unroll
  for (int nn = 0; nn < 32; ++nn) CTX[((size_t)b * 32 + nn) * D + d] = acc[nn];
}

__device__ __forceinline__ float blockSum(float v, volatile float* red, int tid) {
#pragma unroll
  for (int off = 32; off > 0; off >>= 1) v += __shfl_down(v, off);
  __syncthreads();
  if ((tid & 63) == 0) red[tid >> 6] = v;
  __syncthreads();
  return red[0] + red[1] + red[2] + red[3];
}

// ---------------- LayerNorm + final dots
__global__ __launch_bounds__(256) void ln_dot_kernel(
    const float* __restrict__ CTX, const short* __restrict__ MOEb,
    const float* __restrict__ ecls, const float* __restrict__ mcls,
    const float* __restrict__ ln_w, const float* __restrict__ ln_b,
    float* __restrict__ out) {
  __shared__ float red[4];
  int bn = blockIdx.x;
  int b = bn >> 5, n = bn & 31;
  int tid = threadIdx.x;
  const float* cr = CTX + (size_t)bn * D;
  float ctx[3];
#pragma unroll
  for (int r = 0; r < 3; ++r) ctx[r] = cr[tid + r * 256];
  float mu = blockSum(ctx[0] + ctx[1] + ctx[2], red, tid) * (1.f / 768.f);
  float vs = 0.f;
#pragma unroll
  for (int r = 0; r < 3; ++r) { float c = ctx[r] - mu; vs += c * c; }
  float var = blockSum(vs, red, tid) * (1.f / 768.f);
  float rstd = rsqrtf(var + 1e-5f);
  const short* em = MOEb + (size_t)(n * 129) * D;
  float g2l_p = 0.f, g2g_p = 0.f;
#pragma unroll
  for (int r = 0; r < 3; ++r) {
    int d = tid + r * 256;
    float cl = (ctx[r] - mu) * rstd * ln_w[d] + ln_b[d];
    g2l_p += bf2f(em[d]) * cl;
    g2g_p += mcls[(size_t)b * D + d] * ecls[(size_t)n * D + d];
  }
  float g2l = blockSum(g2l_p, red, tid);
  float g2g = blockSum(g2g_p, red, tid);
  if (tid == 0) out[bn] = 0.5f * (g2l + g2g);
}

extern "C" void kernel_launch(void* const* d_in, const int* in_sizes, int n_in,
                              void* d_out, int out_size, void* d_ws, size_t ws_size,
                              hipStream_t stream) {
  const float* ecls   = (const float*)d_in[0];
  const float* etok   = (const float*)d_in[1];
  const float* mcls   = (const float*)d_in[2];
  const float* mtok   = (const float*)d_in[3];
  const float* gate_w = (const float*)d_in[4];
  const float* gate_b = (const float*)d_in[5];
  const float* exp_w  = (const float*)d_in[6];
  const float* exp_b  = (const float*)d_in[7];
  const float* wq     = (const float*)d_in[8];
  const float* bq     = (const float*)d_in[9];
  const float* wk     = (const float*)d_in[10];
  const float* bk     = (const float*)d_in[11];
  const float* wv     = (const float*)d_in[12];
  const float* bv     = (const float*)d_in[13];
  const float* ln_w   = (const float*)d_in[14];
  const float* ln_b   = (const float*)d_in[15];
  float* outp = (float*)d_out;

  char* ws = (char*)d_ws;
  // region A: EO (19,021,824 B) -> later reused for Qb/Kb/V
  short* EO    = (short*)(ws + 0);
  short* Qb    = (short*)(ws + 0);              //  6,291,456 B
  short* Kb    = (short*)(ws + 6291456);        //  3,145,728 B
  float* V     = (float*)(ws + 9437184);        //  6,291,456 B (ends 15,728,640)
  short* MOEb  = (short*)(ws + 19021824);       //  9,510,912 B
  short* expwT = (short*)(ws + 28532736);       //  9,437,184 B
  short* wT    = (short*)(ws + 37969920);       //  3,538,944 B
  float* PBAR  = (float*)(ws + 41508864);       //    262,144 B
  float* CTX   = (float*)(ws + 41771008);       //  1,572,864 B (ends 43,343,872)
  int*   te1   = (int*)  (ws + 43343872);       //     24,768 B
  int*   te2   = (int*)  (ws + 43368640);
  float* tw1   = (float*)(ws + 43393408);
  float* tw2   = (float*)(ws + 43418176);
  int*   slot1 = (int*)  (ws + 43442944);
  int*   slot2 = (int*)  (ws + 43467712);
  int*   lst_tok  = (int*)(ws + 43492480);      //     49,536 B
  int*   localcnt = (int*)(ws + 43542016);      //        800 B
  int*   cnt   = (int*)  (ws + 43542816);       //         32 B
  int*   basee = (int*)  (ws + 43542848);       //         32 B  (total 43,542,880)

  gate_kernel<<<NTOK / 4, 256, 0, stream>>>(ecls, etok, mcls, mtok, gate_w, gate_b,
                                            te1, te2, tw1, tw2);
  count_kernel<<<NCBLK, 256, 0, stream>>>(te1, te2, localcnt);
  compact_kernel<<<NCBLK, 256, 0, stream>>>(te1, te2, localcnt, lst_tok, slot1, slot2,
                                            cnt, basee);
  tcvt_kernel<<<dim3(12, 12, 11), 256, 0, stream>>>(exp_w, wq, wk, wv, expwT, wT);
  moe_kernel<<<dim3(97, 6, 8), 256, 0, stream>>>(ecls, etok, mcls, mtok,
                                                 expwT, cnt, basee, lst_tok, EO);
  combine_kernel<<<2322, 256, 0, stream>>>(EO, te1, te2, tw1, tw2, slot1, slot2,
                                           exp_b, MOEb);
  qkv_kernel<<<dim3(64, 6, 3), 256, 0, stream>>>(MOEb, wT, bq, bk, bv, Qb, Kb, V);
  attn_kernel<<<dim3(16, 32), 256, 0, stream>>>(Qb, Kb, PBAR);
  pv_kernel<<<dim3(16, 3), 256, 0, stream>>>(PBAR, V, CTX);
  ln_dot_kernel<<<512, 256, 0, stream>>>(CTX, MOEb, ecls, mcls, ln_w, ln_b, outp);
}